// Round 5
// baseline (259.672 us; speedup 1.0000x reference)
//
#include <hip/hip_runtime.h>
#include <hip/hip_bf16.h>
#include <hip/hip_fp16.h>

typedef _Float16 f16x8  __attribute__((ext_vector_type(8)));
typedef __fp16   h16x2  __attribute__((ext_vector_type(2)));
typedef float    f32x4  __attribute__((ext_vector_type(4)));
typedef float    f32x16 __attribute__((ext_vector_type(16)));

#define KDIM       384
#define MBLK       64
#define NEDGE      800000
#define NNODES     50000
#define NODE_ELEMS (NNODES * 128)          // 6.4M f16 = 12.8 MB
#define WP_ELEMS   49152                    // 24 ks * 4 nt * 64 lanes * 8
#define HRPAD      136                      // rbf LDS row stride (f16)

__device__ __forceinline__ float fast_swish(float v) {
  return v * __builtin_amdgcn_rcpf(1.0f + __expf(-v));
}

__device__ __forceinline__ void pack8(_Float16* dst, float4 a, float4 b) {
  union { h16x2 h[4]; f16x8 v; } u;
  u.h[0] = __builtin_amdgcn_cvt_pkrtz(a.x, a.y);
  u.h[1] = __builtin_amdgcn_cvt_pkrtz(a.z, a.w);
  u.h[2] = __builtin_amdgcn_cvt_pkrtz(b.x, b.y);
  u.h[3] = __builtin_amdgcn_cvt_pkrtz(b.z, b.w);
  *(f16x8*)dst = u.v;
}

// node[n][c] = c<64 ? resi_w[x[2n]][c] : atom_w[x[2n+1]][c-64], as f16.
__global__ void prep_node_kernel(const int* __restrict__ x,
                                 const float* __restrict__ resi_w,
                                 const float* __restrict__ atom_w,
                                 _Float16* __restrict__ node) {
  int idx = blockIdx.x * 256 + threadIdx.x;      // 800000 exactly
  int n = idx >> 4, cg = idx & 15;
  int isAtom = cg >> 3;
  int off = (cg & 7) << 3;
  int sel = x[(n << 1) + isAtom];
  const float4* s4 = (const float4*)((isAtom ? atom_w : resi_w) + sel * 64 + off);
  float4 v0 = s4[0], v1 = s4[1];
  pack8(node + n * 128 + cg * 8, v0, v1);
}

// Wp[((ks*4+nt)*64 + l)*8 + e] = W_lin[nt*32 + (l&31)][ks*16 + (l>>5)*8 + e]   (32x32x16)
// Wrp[(nt*64 + l)*8 + e]       = k<6 ? W_rbf[nt*16+(l&15)][k] : 0,  k=(l>>4)*8+e  (16x16x32)
__global__ void pack_w_kernel(const float* __restrict__ W_lin,
                              const float* __restrict__ W_rbf,
                              _Float16* __restrict__ Wp,
                              _Float16* __restrict__ Wrp) {
  int idx = blockIdx.x * 256 + threadIdx.x;
  if (idx < WP_ELEMS) {
    int e  = idx & 7;
    int l  = (idx >> 3) & 63;
    int nt = (idx >> 9) & 3;
    int ks = idx >> 11;                        // 0..23
    int n  = nt * 32 + (l & 31);
    int k  = ks * 16 + ((l >> 5) << 3) + e;
    Wp[idx] = (_Float16)W_lin[n * KDIM + k];
  } else if (idx < WP_ELEMS + 4096) {
    int idx2 = idx - WP_ELEMS;
    int e  = idx2 & 7;
    int l  = (idx2 >> 3) & 63;
    int nt = idx2 >> 9;
    int k  = ((l >> 4) << 3) + e;
    float v = (k < 6) ? W_rbf[(nt * 16 + (l & 15)) * 6 + k] : 0.0f;
    Wrp[idx2] = (_Float16)v;
  }
}

__global__ __launch_bounds__(256, 4)
void embed_main_kernel(const float* __restrict__ rbf,
                       const int* __restrict__ gi,
                       const int* __restrict__ gj,
                       const float* __restrict__ b_rbf,
                       const float* __restrict__ b_lin,
                       const _Float16* __restrict__ node,
                       const _Float16* __restrict__ Wp,
                       const _Float16* __restrict__ Wrp,
                       float* __restrict__ out) {
  __shared__ alignas(16) _Float16 hr[MBLK][HRPAD];   // rbf_h tile, 17.4 KB
  const int tid  = threadIdx.x;
  const int e0   = blockIdx.x * MBLK;
  const int lane = tid & 63;
  const int wave = tid >> 6;
  const int m    = wave >> 1;         // 32-row strip
  const int nb   = (wave & 1) * 2;    // first of two 32-col tiles
  const int c5   = lane & 31;
  const int g2   = lane >> 5;

  // ---- Issue node-row fragment loads for both endpoints up front
  const int erow = e0 + (m << 5) + c5;
  const int ni = gi[erow];
  const int nj = gj[erow];
  const f16x8* Ai = (const f16x8*)(node + ni * 128) + g2;
  const f16x8* Aj = (const f16x8*)(node + nj * 128) + g2;
  f16x8 ai[8], aj[8];
  #pragma unroll
  for (int k = 0; k < 8; ++k) { ai[k] = Ai[2 * k]; aj[k] = Aj[2 * k]; }

  // ---- rbf_h = swish(rbf @ W_rbf^T + b_rbf), 16x16x32 MFMA (K pad 6->32) -> LDS
  {
    const int g = lane >> 4;
    const int c = lane & 15;
    f16x8 ra = {0, 0, 0, 0, 0, 0, 0, 0};
    if (g == 0) {
      const float* rp = rbf + (size_t)(e0 + wave * 16 + c) * 6;
      ra[0] = (_Float16)rp[0]; ra[1] = (_Float16)rp[1]; ra[2] = (_Float16)rp[2];
      ra[3] = (_Float16)rp[3]; ra[4] = (_Float16)rp[4]; ra[5] = (_Float16)rp[5];
    }
    const f16x8* wrb = (const f16x8*)Wrp + lane;
    #pragma unroll
    for (int nt = 0; nt < 8; ++nt) {
      f16x8 rb = wrb[nt * 64];
      f32x4 d = __builtin_amdgcn_mfma_f32_16x16x32_f16(ra, rb,
                  (f32x4){0.f, 0.f, 0.f, 0.f}, 0, 0, 0);
      float bb = b_rbf[nt * 16 + c];
      #pragma unroll
      for (int r = 0; r < 4; ++r) {
        float vv = d[r] + bb;
        hr[wave * 16 + 4 * g + r][nt * 16 + c] = (_Float16)fast_swish(vv);
      }
    }
  }
  __syncthreads();

  // ---- K-loop: 24 steps of 32x32x16, two N-tiles per wave
  const f16x8* wp2 = (const f16x8*)Wp + lane;
  f32x16 acc0 = {};
  f32x16 acc1 = {};

  #pragma unroll
  for (int ks = 0; ks < 8; ++ks) {
    f16x8 a = ai[ks];
    acc0 = __builtin_amdgcn_mfma_f32_32x32x16_f16(a, wp2[(ks * 4 + nb) * 64],     acc0, 0, 0, 0);
    acc1 = __builtin_amdgcn_mfma_f32_32x32x16_f16(a, wp2[(ks * 4 + nb + 1) * 64], acc1, 0, 0, 0);
  }
  #pragma unroll
  for (int ks = 8; ks < 16; ++ks) {
    f16x8 a = aj[ks - 8];
    acc0 = __builtin_amdgcn_mfma_f32_32x32x16_f16(a, wp2[(ks * 4 + nb) * 64],     acc0, 0, 0, 0);
    acc1 = __builtin_amdgcn_mfma_f32_32x32x16_f16(a, wp2[(ks * 4 + nb + 1) * 64], acc1, 0, 0, 0);
  }
  const _Float16* hbase = &hr[(m << 5) + c5][g2 << 3];
  #pragma unroll
  for (int ks = 16; ks < 24; ++ks) {
    f16x8 a = *(const f16x8*)(hbase + (ks - 16) * 16);
    acc0 = __builtin_amdgcn_mfma_f32_32x32x16_f16(a, wp2[(ks * 4 + nb) * 64],     acc0, 0, 0, 0);
    acc1 = __builtin_amdgcn_mfma_f32_32x32x16_f16(a, wp2[(ks * 4 + nb + 1) * 64], acc1, 0, 0, 0);
  }

  // ---- Epilogue: +bias, swish, store. D: col=lane&31, row=(reg&3)+8*(reg>>2)+4*g2
  const int colA = (wave & 1) * 64 + c5;
  const int colB = colA + 32;
  const float blA = b_lin[colA];
  const float blB = b_lin[colB];
  #pragma unroll
  for (int reg = 0; reg < 16; ++reg) {
    int row = (reg & 3) + 8 * (reg >> 2) + 4 * g2;
    float* orow = out + (size_t)(e0 + (m << 5) + row) * 128;
    orow[colA] = fast_swish(acc0[reg] + blA);
    orow[colB] = fast_swish(acc1[reg] + blB);
  }
}

extern "C" void kernel_launch(void* const* d_in, const int* in_sizes, int n_in,
                              void* d_out, int out_size, void* d_ws, size_t ws_size,
                              hipStream_t stream) {
  const int*   x      = (const int*)d_in[0];
  const float* rbf    = (const float*)d_in[1];
  const int*   gi     = (const int*)d_in[2];
  const int*   gj     = (const int*)d_in[3];
  const float* resi_w = (const float*)d_in[4];
  const float* atom_w = (const float*)d_in[5];
  const float* W_rbf  = (const float*)d_in[6];
  const float* b_rbf  = (const float*)d_in[7];
  const float* W_lin  = (const float*)d_in[8];
  const float* b_lin  = (const float*)d_in[9];
  float* out = (float*)d_out;

  _Float16* node = (_Float16*)d_ws;                       // 12.8 MB
  _Float16* Wp   = (_Float16*)d_ws + NODE_ELEMS;          // 96 KB
  _Float16* Wrp  = (_Float16*)d_ws + NODE_ELEMS + WP_ELEMS; // 8 KB

  hipLaunchKernelGGL(prep_node_kernel, dim3(NNODES * 16 / 256), dim3(256), 0, stream,
                     x, resi_w, atom_w, node);
  hipLaunchKernelGGL(pack_w_kernel, dim3(208), dim3(256), 0, stream,
                     W_lin, W_rbf, Wp, Wrp);
  hipLaunchKernelGGL(embed_main_kernel, dim3(NEDGE / MBLK), dim3(256), 0, stream,
                     rbf, gi, gj, b_rbf, b_lin, node, Wp, Wrp, out);
}